// Round 16
// baseline (108.045 us; speedup 1.0000x reference)
//
#include <hip/hip_runtime.h>
#include <cstdint>

#define EPS 1e-5f

static __device__ inline unsigned f2bf(float f) {   // RNE bf16 in low 16 bits
    unsigned u = __float_as_uint(f);
    unsigned r = u + 0x7FFFu + ((u >> 16) & 1u);
    return r >> 16;
}
static __device__ inline float bflo(unsigned u) { return __uint_as_float(u << 16); }
static __device__ inline float bfhi(unsigned u) { return __uint_as_float(u & 0xFFFF0000u); }

// ============ K1: per-plane row/col sums + bf16 copy; XCD-affine plane mapping ============
__global__ __launch_bounds__(256) void k1_sums(const float* __restrict__ x,
                                               unsigned short* __restrict__ xh,
                                               float* __restrict__ rowsum,
                                               float* __restrict__ colsum) {
    // block b -> plane ((b&255)<<3)|(b>>8): all 8 planes of bg processed on XCD bg%8
    const int p = ((blockIdx.x & 255) << 3) | (blockIdx.x >> 8);
    const int t = threadIdx.x;
    const int rgrp = t >> 4;     // row within 16-row chunk
    const int cblk = t & 15;     // 8-col block
    const float* xp = x + (size_t)p * 16384;
    unsigned short* xhp = xh + (size_t)p * 16384;
    __shared__ float red[16][128];
    float cp[8];
#pragma unroll
    for (int j = 0; j < 8; ++j) cp[j] = 0.f;

#pragma unroll
    for (int i = 0; i < 8; ++i) {
        int row = i * 16 + rgrp;
        const float* rp = xp + row * 128 + cblk * 8;
        float4 a = *(const float4*)rp;
        float4 b = *(const float4*)(rp + 4);
        uint4 h;
        h.x = f2bf(a.x) | (f2bf(a.y) << 16);
        h.y = f2bf(a.z) | (f2bf(a.w) << 16);
        h.z = f2bf(b.x) | (f2bf(b.y) << 16);
        h.w = f2bf(b.z) | (f2bf(b.w) << 16);
        *(uint4*)(xhp + row * 128 + cblk * 8) = h;
        cp[0] += a.x; cp[1] += a.y; cp[2] += a.z; cp[3] += a.w;
        cp[4] += b.x; cp[5] += b.y; cp[6] += b.z; cp[7] += b.w;
        float rs = a.x + a.y + a.z + a.w + b.x + b.y + b.z + b.w;
        rs += __shfl_xor(rs, 1); rs += __shfl_xor(rs, 2);
        rs += __shfl_xor(rs, 4); rs += __shfl_xor(rs, 8);
        if (cblk == 0) rowsum[p * 128 + row] = rs;
    }
    *(float4*)&red[rgrp][cblk * 8]     = make_float4(cp[0], cp[1], cp[2], cp[3]);
    *(float4*)&red[rgrp][cblk * 8 + 4] = make_float4(cp[4], cp[5], cp[6], cp[7]);
    __syncthreads();
    if (t < 128) {
        float s = 0.f;
#pragma unroll
        for (int j = 0; j < 16; ++j) s += red[j][t];
        colsum[p * 128 + t] = s;
    }
}

// ============ K2: per-bg gates + analytic x2-mean + x21 + stats(bf16,16B) + alpha/beta [proven R12] ============
__global__ __launch_bounds__(1024) void k2_mid(
    const float* __restrict__ x, const unsigned short* __restrict__ xh,
    const float* __restrict__ rowsum, const float* __restrict__ colsum,
    const float* __restrict__ w1, const float* __restrict__ b1,
    const float* __restrict__ w3, const float* __restrict__ b3,
    const float* __restrict__ gn_w, const float* __restrict__ gn_b,
    float* __restrict__ sh, float* __restrict__ sw,
    float* __restrict__ wt, float* __restrict__ alpha, float* __restrict__ beta)
{
    __shared__ float rs[1024], cs[1024], shl[1024], swl[1024];
    __shared__ float w1l[64], b1l[8], corn[32], S[8], Tm[72], m2[8], x11[8], x21l[8];
    __shared__ float ps[32], qs[32], bs[8];
    __shared__ float btl;
    const int bg = blockIdx.x;
    const int t  = threadIdx.x;
    const int sg = t >> 8, ts = t & 255;
    const size_t pbase = (size_t)(bg * 8) * 16384;

    rs[t] = rowsum[bg * 1024 + t];
    cs[t] = colsum[bg * 1024 + t];
    if (t < 64) w1l[t] = w1[t];
    if (t >= 64 && t < 72) b1l[t - 64] = b1[t - 64];
    if (t >= 128 && t < 136) {
        int i = t - 128;
        const float* xpp = x + pbase + (size_t)i * 16384;
        corn[i * 4 + 0] = xpp[0];
        corn[i * 4 + 1] = xpp[127];
        corn[i * 4 + 2] = xpp[127 * 128];
        corn[i * 4 + 3] = xpp[127 * 128 + 127];
    }
    if (t == 200) {   // x11 = softmax(gn_b)
        float mx = gn_b[0];
        for (int i = 1; i < 8; ++i) mx = fmaxf(mx, gn_b[i]);
        float e[8], s = 0.f;
        for (int i = 0; i < 8; ++i) { e[i] = __expf(gn_b[i] - mx); s += e[i]; }
        for (int i = 0; i < 8; ++i) x11[i] = e[i] / s;
    }
    __syncthreads();

    if (t == 300) {   // btilde (block-local)
        float a = 0.f;
        for (int o = 0; o < 8; ++o) a += x11[o] * b3[o];
        btl = a;
    }
    {   // gates: 8 o-channels x 128 positions (EXACT f32 sums)
        int o = t >> 7, y = t & 127;
        const float inv128 = 1.f / 128.f;
        float ar = b1l[o], ac = ar;
        for (int i = 0; i < 8; ++i) {
            float w = w1l[o * 8 + i];
            ar += w * rs[i * 128 + y] * inv128;
            ac += w * cs[i * 128 + y] * inv128;
        }
        float sv = 1.f / (1.f + __expf(-ar));
        float wv = 1.f / (1.f + __expf(-ac));
        shl[o * 128 + y] = sv;  sh[(bg * 8 + o) * 128 + y] = sv;
        swl[o * 128 + y] = wv;  sw[(bg * 8 + o) * 128 + y] = wv;
    }
    if (t < 8) {
        float s = 0.f;
        for (int y = 0; y < 128; ++y) s += rs[t * 128 + y];
        S[t] = s;
    }
    __syncthreads();

    if (t < 72) {   // shifted-window sums for SAME zero padding
        int i = t / 9, ky = (t % 9) / 3, kx = t % 3;
        float v = S[i];
        if (ky == 0) v -= rs[i * 128 + 127]; else if (ky == 2) v -= rs[i * 128 + 0];
        if (kx == 0) v -= cs[i * 128 + 127]; else if (kx == 2) v -= cs[i * 128 + 0];
        if (ky == 0 && kx == 0) v += corn[i * 4 + 3];
        if (ky == 0 && kx == 2) v += corn[i * 4 + 2];
        if (ky == 2 && kx == 0) v += corn[i * 4 + 1];
        if (ky == 2 && kx == 2) v += corn[i * 4 + 0];
        Tm[t] = v;
    }
    __syncthreads();

    if (t < 8) {
        float acc = 0.f;
        for (int j = 0; j < 72; ++j) acc += w3[t * 72 + j] * Tm[j];
        m2[t] = b3[t] + acc * (1.f / 16384.f);
    }
    if (bg == 0 && t >= 128 && t < 200) {   // collapsed conv weights
        int j = t - 128;
        float a = 0.f;
        for (int o = 0; o < 8; ++o) a += x11[o] * w3[o * 72 + j];
        wt[j] = a;
    }
    __syncthreads();

    if (t == 0) {   // x21 = softmax(m2)
        float mx = m2[0];
        for (int i = 1; i < 8; ++i) mx = fmaxf(mx, m2[i]);
        float e[8], s = 0.f;
        for (int i = 0; i < 8; ++i) { e[i] = __expf(m2[i] - mx); s += e[i]; }
        for (int i = 0; i < 8; ++i) x21l[i] = e[i] / s;
    }
    __syncthreads();

    // stats: gated sum & sumsq per plane from bf16 copy, uint4 (16B) loads
    {
        const int rgrp = ts >> 4, cblk = ts & 15;
        for (int half = 0; half < 2; ++half) {
            int pi = half * 4 + sg;
            const unsigned short* xp = xh + pbase + (size_t)pi * 16384;
            float4 swa = *(const float4*)(swl + pi * 128 + cblk * 8);
            float4 swb = *(const float4*)(swl + pi * 128 + cblk * 8 + 4);
            float s = 0.f, q = 0.f;
#pragma unroll
            for (int i = 0; i < 8; ++i) {
                int row = i * 16 + rgrp;
                uint4 h = *(const uint4*)(xp + row * 128 + cblk * 8);
                float shv = shl[pi * 128 + row];
                float g0 = bflo(h.x) * shv * swa.x;
                float g1 = bfhi(h.x) * shv * swa.y;
                float g2 = bflo(h.y) * shv * swa.z;
                float g3 = bfhi(h.y) * shv * swa.w;
                float g4 = bflo(h.z) * shv * swb.x;
                float g5 = bfhi(h.z) * shv * swb.y;
                float g6 = bflo(h.w) * shv * swb.z;
                float g7 = bfhi(h.w) * shv * swb.w;
                s += g0 + g1 + g2 + g3 + g4 + g5 + g6 + g7;
                q += g0*g0 + g1*g1 + g2*g2 + g3*g3 + g4*g4 + g5*g5 + g6*g6 + g7*g7;
            }
            for (int m = 32; m; m >>= 1) { s += __shfl_xor(s, m); q += __shfl_xor(q, m); }
            if ((ts & 63) == 0) {
                ps[pi * 4 + (ts >> 6)] = s;
                qs[pi * 4 + (ts >> 6)] = q;
            }
        }
    }
    __syncthreads();
    if (t < 8) {
        float s = 0.f, q = 0.f;
        for (int j = 0; j < 4; ++j) { s += ps[t * 4 + j]; q += qs[t * 4 + j]; }
        float mu  = s * (1.f / 16384.f);
        float ex2 = q * (1.f / 16384.f);
        float var = ex2 - mu * mu;
        float inv = rsqrtf(var + EPS);
        float x21v = x21l[t];
        alpha[bg * 8 + t] = x21v * inv * gn_w[t];
        bs[t] = x21v * (gn_b[t] - mu * inv * gn_w[t]);
    }
    __syncthreads();
    if (t == 0) {
        float s = btl;
        for (int i = 0; i < 8; ++i) s += bs[i];
        beta[bg] = s;
    }
}

// ============ K3: collapsed conv + gating + sigmoid + output; XCD-affine block mapping ============
__global__ __launch_bounds__(512, 4) void k3_out(
    const unsigned short* __restrict__ xh, const float* __restrict__ sh,
    const float* __restrict__ sw, const float* __restrict__ alpha,
    const float* __restrict__ beta, const float* __restrict__ wt,
    float* __restrict__ out)
{
    __shared__ float tl[8 * 18 * 128];   // 73728 B
    __shared__ float wtl[72], al[8], shl[128];
    __shared__ float betal;
    // block b -> (bg = b&255, slab = b>>8): XCD = bg%8, matches k1/k2 xh producers
    const int blk = blockIdx.x, bg = blk & 255, r0 = (blk >> 8) * 16;
    const int t = threadIdx.x, lane = t & 31, w = t >> 5;   // w in [0,16)
    const size_t pbase = (size_t)(bg * 8) * 16384;

    // stage: 2304 uint4-slots (8 bf16 each) = 8ch x 18 rows x 16 slots
#pragma unroll
    for (int it = 0; it < 5; ++it) {
        int idx = it * 512 + t;                 // [0, 2560); valid < 2304
        if (idx < 2304) {
            int ch  = idx / 288;                // 18*16 = 288
            int rem = idx - ch * 288;
            int row = rem >> 4;
            int s8  = rem & 15;
            int g = r0 - 1 + row;
            float4 va = {0.f,0.f,0.f,0.f}, vb = {0.f,0.f,0.f,0.f};
            if ((unsigned)g < 128u) {
                uint4 h = *(const uint4*)(xh + pbase + (size_t)ch * 16384 + g * 128 + s8 * 8);
                va.x = bflo(h.x); va.y = bfhi(h.x); va.z = bflo(h.y); va.w = bfhi(h.y);
                vb.x = bflo(h.z); vb.y = bfhi(h.z); vb.z = bflo(h.w); vb.w = bfhi(h.w);
            }
            float* d = tl + ch * 2304 + row * 128 + s8 * 8;
            *(float4*)d = va;
            *(float4*)(d + 4) = vb;
        }
    }
    if (t < 72) wtl[t] = wt[t];
    if (t >= 128 && t < 136) al[t - 128] = alpha[bg * 8 + (t - 128)];
    if (t == 136) betal = beta[bg];
    if (t >= 256 && t < 384) {
        int u = t - 256;    // u>>4 = channel, u&15 = row in slab
        shl[u] = sh[(size_t)(bg * 8 + (u >> 4)) * 128 + r0 + (u & 15)];
    }
    __syncthreads();

    const int y  = r0 + w;
    const int x0 = lane * 4;
    float4 acc = {betal, betal, betal, betal};
    float4 gv[8];

#pragma unroll
    for (int ch = 0; ch < 8; ++ch) {
        const float* base = tl + ch * 2304 + w * 128 + x0;   // tile row w = global y-1
#pragma unroll
        for (int r = 0; r < 3; ++r) {
            float4 va = *(const float4*)(base + r * 128);
            float xm1 = __shfl_up(va.w, 1, 32);   if (lane == 0)  xm1 = 0.f;
            float xp4 = __shfl_down(va.x, 1, 32); if (lane == 31) xp4 = 0.f;
            float w0 = wtl[ch * 9 + r * 3 + 0];
            float w1v = wtl[ch * 9 + r * 3 + 1];
            float w2 = wtl[ch * 9 + r * 3 + 2];
            acc.x += w0 * xm1  + w1v * va.x + w2 * va.y;
            acc.y += w0 * va.x + w1v * va.y + w2 * va.z;
            acc.z += w0 * va.y + w1v * va.z + w2 * va.w;
            acc.w += w0 * va.z + w1v * va.w + w2 * xp4;
            if (r == 1) gv[ch] = va;   // center row = x[ch][y][x0..3]
        }
        float as = al[ch] * shl[(ch << 4) + w];
        float4 s4 = *(const float4*)(sw + (size_t)(bg * 8 + ch) * 128 + x0);  // L1-hot
        acc.x += as * s4.x * gv[ch].x;
        acc.y += as * s4.y * gv[ch].y;
        acc.z += as * s4.z * gv[ch].z;
        acc.w += as * s4.w * gv[ch].w;
    }

    float4 sg;
    sg.x = 1.f / (1.f + __expf(-acc.x));
    sg.y = 1.f / (1.f + __expf(-acc.y));
    sg.z = 1.f / (1.f + __expf(-acc.z));
    sg.w = 1.f / (1.f + __expf(-acc.w));

    const size_t ob = pbase + (size_t)y * 128 + x0;
#pragma unroll
    for (int c = 0; c < 8; ++c) {
        float4 o4 = { gv[c].x * sg.x, gv[c].y * sg.y, gv[c].z * sg.z, gv[c].w * sg.w };
        *(float4*)(out + ob + (size_t)c * 16384) = o4;
    }
}

extern "C" void kernel_launch(void* const* d_in, const int* in_sizes, int n_in,
                              void* d_out, int out_size, void* d_ws, size_t ws_size,
                              hipStream_t stream) {
    (void)in_sizes; (void)n_in; (void)out_size; (void)ws_size;
    const float* x    = (const float*)d_in[0];
    const float* w1   = (const float*)d_in[1];
    const float* b1   = (const float*)d_in[2];
    const float* w3   = (const float*)d_in[3];
    const float* b3   = (const float*)d_in[4];
    const float* gn_w = (const float*)d_in[5];
    const float* gn_b = (const float*)d_in[6];
    float* out = (float*)d_out;
    float* ws  = (float*)d_ws;

    float* rowsum = ws;                         // 2048*128 f32
    float* colsum = ws + 262144;                // 2048*128 f32
    float* sh     = ws + 524288;                // 2048*128 f32
    float* sw     = ws + 786432;                // 2048*128 f32
    float* alpha  = ws + 1048576;               // 2048
    float* beta   = ws + 1050624;               // 256
    float* wt     = ws + 1050880;               // 72
    unsigned short* xh = (unsigned short*)(ws + 1051136);  // 33.5M bf16 = 67 MB

    hipLaunchKernelGGL(k1_sums, dim3(2048), dim3(256),  0, stream, x, xh, rowsum, colsum);
    hipLaunchKernelGGL(k2_mid,  dim3(256),  dim3(1024), 0, stream, x, xh, rowsum, colsum,
                       w1, b1, w3, b3, gn_w, gn_b, sh, sw, wt, alpha, beta);
    hipLaunchKernelGGL(k3_out,  dim3(2048), dim3(512),  0, stream, xh, sh, sw,
                       alpha, beta, wt, out);
}

// Round 17
// 101.395 us; speedup vs baseline: 1.0656x; 1.0656x over previous
//
#include <hip/hip_runtime.h>
#include <cstdint>

#define EPS 1e-5f

static __device__ inline unsigned f2bf(float f) {   // RNE bf16 in low 16 bits
    unsigned u = __float_as_uint(f);
    unsigned r = u + 0x7FFFu + ((u >> 16) & 1u);
    return r >> 16;
}
static __device__ inline float bflo(unsigned u) { return __uint_as_float(u << 16); }
static __device__ inline float bfhi(unsigned u) { return __uint_as_float(u & 0xFFFF0000u); }

// ============ K1: per-plane row/col sums + bf16 copy (16B/lane stores) [champion R12] ============
__global__ __launch_bounds__(256) void k1_sums(const float* __restrict__ x,
                                               unsigned short* __restrict__ xh,
                                               float* __restrict__ rowsum,
                                               float* __restrict__ colsum) {
    const int p = blockIdx.x, t = threadIdx.x;
    const int rgrp = t >> 4;     // row within 16-row chunk
    const int cblk = t & 15;     // 8-col block
    const float* xp = x + (size_t)p * 16384;
    unsigned short* xhp = xh + (size_t)p * 16384;
    __shared__ float red[16][128];
    float cp[8];
#pragma unroll
    for (int j = 0; j < 8; ++j) cp[j] = 0.f;

#pragma unroll
    for (int i = 0; i < 8; ++i) {
        int row = i * 16 + rgrp;
        const float* rp = xp + row * 128 + cblk * 8;
        float4 a = *(const float4*)rp;
        float4 b = *(const float4*)(rp + 4);
        uint4 h;
        h.x = f2bf(a.x) | (f2bf(a.y) << 16);
        h.y = f2bf(a.z) | (f2bf(a.w) << 16);
        h.z = f2bf(b.x) | (f2bf(b.y) << 16);
        h.w = f2bf(b.z) | (f2bf(b.w) << 16);
        *(uint4*)(xhp + row * 128 + cblk * 8) = h;
        cp[0] += a.x; cp[1] += a.y; cp[2] += a.z; cp[3] += a.w;
        cp[4] += b.x; cp[5] += b.y; cp[6] += b.z; cp[7] += b.w;
        float rs = a.x + a.y + a.z + a.w + b.x + b.y + b.z + b.w;
        rs += __shfl_xor(rs, 1); rs += __shfl_xor(rs, 2);
        rs += __shfl_xor(rs, 4); rs += __shfl_xor(rs, 8);
        if (cblk == 0) rowsum[p * 128 + row] = rs;
    }
    *(float4*)&red[rgrp][cblk * 8]     = make_float4(cp[0], cp[1], cp[2], cp[3]);
    *(float4*)&red[rgrp][cblk * 8 + 4] = make_float4(cp[4], cp[5], cp[6], cp[7]);
    __syncthreads();
    if (t < 128) {
        float s = 0.f;
#pragma unroll
        for (int j = 0; j < 16; ++j) s += red[j][t];
        colsum[p * 128 + t] = s;
    }
}

// ============ K2: per-bg gates + analytic x2-mean + x21 + stats(bf16,16B) + alpha/beta [champion R12] ============
__global__ __launch_bounds__(1024) void k2_mid(
    const float* __restrict__ x, const unsigned short* __restrict__ xh,
    const float* __restrict__ rowsum, const float* __restrict__ colsum,
    const float* __restrict__ w1, const float* __restrict__ b1,
    const float* __restrict__ w3, const float* __restrict__ b3,
    const float* __restrict__ gn_w, const float* __restrict__ gn_b,
    float* __restrict__ sh, float* __restrict__ sw,
    float* __restrict__ wt, float* __restrict__ alpha, float* __restrict__ beta)
{
    __shared__ float rs[1024], cs[1024], shl[1024], swl[1024];
    __shared__ float w1l[64], b1l[8], corn[32], S[8], Tm[72], m2[8], x11[8], x21l[8];
    __shared__ float ps[32], qs[32], bs[8];
    __shared__ float btl;
    const int bg = blockIdx.x;
    const int t  = threadIdx.x;
    const int sg = t >> 8, ts = t & 255;
    const size_t pbase = (size_t)(bg * 8) * 16384;

    rs[t] = rowsum[bg * 1024 + t];
    cs[t] = colsum[bg * 1024 + t];
    if (t < 64) w1l[t] = w1[t];
    if (t >= 64 && t < 72) b1l[t - 64] = b1[t - 64];
    if (t >= 128 && t < 136) {
        int i = t - 128;
        const float* xpp = x + pbase + (size_t)i * 16384;
        corn[i * 4 + 0] = xpp[0];
        corn[i * 4 + 1] = xpp[127];
        corn[i * 4 + 2] = xpp[127 * 128];
        corn[i * 4 + 3] = xpp[127 * 128 + 127];
    }
    if (t == 200) {   // x11 = softmax(gn_b)
        float mx = gn_b[0];
        for (int i = 1; i < 8; ++i) mx = fmaxf(mx, gn_b[i]);
        float e[8], s = 0.f;
        for (int i = 0; i < 8; ++i) { e[i] = __expf(gn_b[i] - mx); s += e[i]; }
        for (int i = 0; i < 8; ++i) x11[i] = e[i] / s;
    }
    __syncthreads();

    if (t == 300) {   // btilde (block-local)
        float a = 0.f;
        for (int o = 0; o < 8; ++o) a += x11[o] * b3[o];
        btl = a;
    }
    {   // gates: 8 o-channels x 128 positions (EXACT f32 sums)
        int o = t >> 7, y = t & 127;
        const float inv128 = 1.f / 128.f;
        float ar = b1l[o], ac = ar;
        for (int i = 0; i < 8; ++i) {
            float w = w1l[o * 8 + i];
            ar += w * rs[i * 128 + y] * inv128;
            ac += w * cs[i * 128 + y] * inv128;
        }
        float sv = 1.f / (1.f + __expf(-ar));
        float wv = 1.f / (1.f + __expf(-ac));
        shl[o * 128 + y] = sv;  sh[(bg * 8 + o) * 128 + y] = sv;
        swl[o * 128 + y] = wv;  sw[(bg * 8 + o) * 128 + y] = wv;
    }
    if (t < 8) {
        float s = 0.f;
        for (int y = 0; y < 128; ++y) s += rs[t * 128 + y];
        S[t] = s;
    }
    __syncthreads();

    if (t < 72) {   // shifted-window sums for SAME zero padding
        int i = t / 9, ky = (t % 9) / 3, kx = t % 3;
        float v = S[i];
        if (ky == 0) v -= rs[i * 128 + 127]; else if (ky == 2) v -= rs[i * 128 + 0];
        if (kx == 0) v -= cs[i * 128 + 127]; else if (kx == 2) v -= cs[i * 128 + 0];
        if (ky == 0 && kx == 0) v += corn[i * 4 + 3];
        if (ky == 0 && kx == 2) v += corn[i * 4 + 2];
        if (ky == 2 && kx == 0) v += corn[i * 4 + 1];
        if (ky == 2 && kx == 2) v += corn[i * 4 + 0];
        Tm[t] = v;
    }
    __syncthreads();

    if (t < 8) {
        float acc = 0.f;
        for (int j = 0; j < 72; ++j) acc += w3[t * 72 + j] * Tm[j];
        m2[t] = b3[t] + acc * (1.f / 16384.f);
    }
    if (bg == 0 && t >= 128 && t < 200) {   // collapsed conv weights
        int j = t - 128;
        float a = 0.f;
        for (int o = 0; o < 8; ++o) a += x11[o] * w3[o * 72 + j];
        wt[j] = a;
    }
    __syncthreads();

    if (t == 0) {   // x21 = softmax(m2)
        float mx = m2[0];
        for (int i = 1; i < 8; ++i) mx = fmaxf(mx, m2[i]);
        float e[8], s = 0.f;
        for (int i = 0; i < 8; ++i) { e[i] = __expf(m2[i] - mx); s += e[i]; }
        for (int i = 0; i < 8; ++i) x21l[i] = e[i] / s;
    }
    __syncthreads();

    // stats: gated sum & sumsq per plane from bf16 copy, uint4 (16B) loads
    {
        const int rgrp = ts >> 4, cblk = ts & 15;
        for (int half = 0; half < 2; ++half) {
            int pi = half * 4 + sg;
            const unsigned short* xp = xh + pbase + (size_t)pi * 16384;
            float4 swa = *(const float4*)(swl + pi * 128 + cblk * 8);
            float4 swb = *(const float4*)(swl + pi * 128 + cblk * 8 + 4);
            float s = 0.f, q = 0.f;
#pragma unroll
            for (int i = 0; i < 8; ++i) {
                int row = i * 16 + rgrp;
                uint4 h = *(const uint4*)(xp + row * 128 + cblk * 8);
                float shv = shl[pi * 128 + row];
                float g0 = bflo(h.x) * shv * swa.x;
                float g1 = bfhi(h.x) * shv * swa.y;
                float g2 = bflo(h.y) * shv * swa.z;
                float g3 = bfhi(h.y) * shv * swa.w;
                float g4 = bflo(h.z) * shv * swb.x;
                float g5 = bfhi(h.z) * shv * swb.y;
                float g6 = bflo(h.w) * shv * swb.z;
                float g7 = bfhi(h.w) * shv * swb.w;
                s += g0 + g1 + g2 + g3 + g4 + g5 + g6 + g7;
                q += g0*g0 + g1*g1 + g2*g2 + g3*g3 + g4*g4 + g5*g5 + g6*g6 + g7*g7;
            }
            for (int m = 32; m; m >>= 1) { s += __shfl_xor(s, m); q += __shfl_xor(q, m); }
            if ((ts & 63) == 0) {
                ps[pi * 4 + (ts >> 6)] = s;
                qs[pi * 4 + (ts >> 6)] = q;
            }
        }
    }
    __syncthreads();
    if (t < 8) {
        float s = 0.f, q = 0.f;
        for (int j = 0; j < 4; ++j) { s += ps[t * 4 + j]; q += qs[t * 4 + j]; }
        float mu  = s * (1.f / 16384.f);
        float ex2 = q * (1.f / 16384.f);
        float var = ex2 - mu * mu;
        float inv = rsqrtf(var + EPS);
        float x21v = x21l[t];
        alpha[bg * 8 + t] = x21v * inv * gn_w[t];
        bs[t] = x21v * (gn_b[t] - mu * inv * gn_w[t]);
    }
    __syncthreads();
    if (t == 0) {
        float s = btl;
        for (int i = 0; i < 8; ++i) s += bs[i];
        beta[bg] = s;
    }
}

// ============ K3: collapsed conv + gating + sigmoid + output [champion R12] ============
// f32 LDS tile staged from bf16 xh (uint4 16B loads); halo via 2 shuffles; 1 row/thread.
__global__ __launch_bounds__(512, 4) void k3_out(
    const unsigned short* __restrict__ xh, const float* __restrict__ sh,
    const float* __restrict__ sw, const float* __restrict__ alpha,
    const float* __restrict__ beta, const float* __restrict__ wt,
    float* __restrict__ out)
{
    __shared__ float tl[8 * 18 * 128];   // 73728 B
    __shared__ float wtl[72], al[8], shl[128];
    __shared__ float betal;
    const int blk = blockIdx.x, bg = blk >> 3, r0 = (blk & 7) * 16;
    const int t = threadIdx.x, lane = t & 31, w = t >> 5;   // w in [0,16)
    const size_t pbase = (size_t)(bg * 8) * 16384;

    // stage: 2304 uint4-slots (8 bf16 each) = 8ch x 18 rows x 16 slots
#pragma unroll
    for (int it = 0; it < 5; ++it) {
        int idx = it * 512 + t;                 // [0, 2560); valid < 2304
        if (idx < 2304) {
            int ch  = idx / 288;                // 18*16 = 288
            int rem = idx - ch * 288;
            int row = rem >> 4;
            int s8  = rem & 15;
            int g = r0 - 1 + row;
            float4 va = {0.f,0.f,0.f,0.f}, vb = {0.f,0.f,0.f,0.f};
            if ((unsigned)g < 128u) {
                uint4 h = *(const uint4*)(xh + pbase + (size_t)ch * 16384 + g * 128 + s8 * 8);
                va.x = bflo(h.x); va.y = bfhi(h.x); va.z = bflo(h.y); va.w = bfhi(h.y);
                vb.x = bflo(h.z); vb.y = bfhi(h.z); vb.z = bflo(h.w); vb.w = bfhi(h.w);
            }
            float* d = tl + ch * 2304 + row * 128 + s8 * 8;
            *(float4*)d = va;
            *(float4*)(d + 4) = vb;
        }
    }
    if (t < 72) wtl[t] = wt[t];
    if (t >= 128 && t < 136) al[t - 128] = alpha[bg * 8 + (t - 128)];
    if (t == 136) betal = beta[bg];
    if (t >= 256 && t < 384) {
        int u = t - 256;    // u>>4 = channel, u&15 = row in slab
        shl[u] = sh[(size_t)(bg * 8 + (u >> 4)) * 128 + r0 + (u & 15)];
    }
    __syncthreads();

    const int y  = r0 + w;
    const int x0 = lane * 4;
    float4 acc = {betal, betal, betal, betal};
    float4 gv[8];

#pragma unroll
    for (int ch = 0; ch < 8; ++ch) {
        const float* base = tl + ch * 2304 + w * 128 + x0;   // tile row w = global y-1
#pragma unroll
        for (int r = 0; r < 3; ++r) {
            float4 va = *(const float4*)(base + r * 128);
            float xm1 = __shfl_up(va.w, 1, 32);   if (lane == 0)  xm1 = 0.f;
            float xp4 = __shfl_down(va.x, 1, 32); if (lane == 31) xp4 = 0.f;
            float w0 = wtl[ch * 9 + r * 3 + 0];
            float w1v = wtl[ch * 9 + r * 3 + 1];
            float w2 = wtl[ch * 9 + r * 3 + 2];
            acc.x += w0 * xm1  + w1v * va.x + w2 * va.y;
            acc.y += w0 * va.x + w1v * va.y + w2 * va.z;
            acc.z += w0 * va.y + w1v * va.z + w2 * va.w;
            acc.w += w0 * va.z + w1v * va.w + w2 * xp4;
            if (r == 1) gv[ch] = va;   // center row = x[ch][y][x0..3]
        }
        float as = al[ch] * shl[(ch << 4) + w];
        float4 s4 = *(const float4*)(sw + (size_t)(bg * 8 + ch) * 128 + x0);  // L1-hot
        acc.x += as * s4.x * gv[ch].x;
        acc.y += as * s4.y * gv[ch].y;
        acc.z += as * s4.z * gv[ch].z;
        acc.w += as * s4.w * gv[ch].w;
    }

    float4 sg;
    sg.x = 1.f / (1.f + __expf(-acc.x));
    sg.y = 1.f / (1.f + __expf(-acc.y));
    sg.z = 1.f / (1.f + __expf(-acc.z));
    sg.w = 1.f / (1.f + __expf(-acc.w));

    const size_t ob = pbase + (size_t)y * 128 + x0;
#pragma unroll
    for (int c = 0; c < 8; ++c) {
        float4 o4 = { gv[c].x * sg.x, gv[c].y * sg.y, gv[c].z * sg.z, gv[c].w * sg.w };
        *(float4*)(out + ob + (size_t)c * 16384) = o4;
    }
}

extern "C" void kernel_launch(void* const* d_in, const int* in_sizes, int n_in,
                              void* d_out, int out_size, void* d_ws, size_t ws_size,
                              hipStream_t stream) {
    (void)in_sizes; (void)n_in; (void)out_size; (void)ws_size;
    const float* x    = (const float*)d_in[0];
    const float* w1   = (const float*)d_in[1];
    const float* b1   = (const float*)d_in[2];
    const float* w3   = (const float*)d_in[3];
    const float* b3   = (const float*)d_in[4];
    const float* gn_w = (const float*)d_in[5];
    const float* gn_b = (const float*)d_in[6];
    float* out = (float*)d_out;
    float* ws  = (float*)d_ws;

    float* rowsum = ws;                         // 2048*128 f32
    float* colsum = ws + 262144;                // 2048*128 f32
    float* sh     = ws + 524288;                // 2048*128 f32
    float* sw     = ws + 786432;                // 2048*128 f32
    float* alpha  = ws + 1048576;               // 2048
    float* beta   = ws + 1050624;               // 256
    float* wt     = ws + 1050880;               // 72
    unsigned short* xh = (unsigned short*)(ws + 1051136);  // 33.5M bf16 = 67 MB

    hipLaunchKernelGGL(k1_sums, dim3(2048), dim3(256),  0, stream, x, xh, rowsum, colsum);
    hipLaunchKernelGGL(k2_mid,  dim3(256),  dim3(1024), 0, stream, x, xh, rowsum, colsum,
                       w1, b1, w3, b3, gn_w, gn_b, sh, sw, wt, alpha, beta);
    hipLaunchKernelGGL(k3_out,  dim3(2048), dim3(512),  0, stream, xh, sh, sw,
                       alpha, beta, wt, out);
}